// Round 9
// baseline (542.770 us; speedup 1.0000x reference)
//
#include <hip/hip_runtime.h>
#include <hip/hip_fp16.h>

#define TT 800
#define CC 80
#define BB 16
#define SS 128
#define INFV 1e9f
#define NLCB 113          // local chunks per band (904 steps / 8)
#define LAGCH 14          // chunk lag between bands (112 steps >= 98 + 8 + margin)
#define NGC 155           // 113 + 3*14
#define BANDH 200         // rows per band (4 bands x 200 = 800)
#define HALF_PER_BAND (113*50*32)     // 180800
#define HALF_PER_SLOT (4*113*50*32)   // 723200
#define SCALE 14.426950408889634f     // (1/gamma)*log2(e), gamma=0.1

// Bool masks may arrive as 1-byte numpy bools or int32 — detected at runtime.
__device__ inline bool mask_get(const void* p, int idx, int isInt) {
  if (isInt) return ((const int*)p)[idx] != 0;
  return ((const unsigned char*)p)[idx] != 0;
}

__device__ __forceinline__ float fexp2(float x) {
#if __has_builtin(__builtin_amdgcn_exp2f)
  return __builtin_amdgcn_exp2f(x);
#else
  return __expf(x * 0.6931471805599453f);
#endif
}
__device__ __forceinline__ float flog2(float x) {
#if __has_builtin(__builtin_amdgcn_logf)
  return __builtin_amdgcn_logf(x);
#else
  return __logf(x) * 1.4426950408889634f;
#endif
}
__device__ __forceinline__ float fmin3(float a, float b, float c) {
  return fminf(fminf(a, b), c);
}

// Wave-wide shift-up-by-1 on the VALU pipe (no LDS): DPP compose.
__device__ __forceinline__ float shift_up1(float x) {
  int xi = __builtin_bit_cast(int, x);
  int b = __builtin_amdgcn_update_dpp(xi, xi, 0x143, 0xf, 0xf, false); // row_bcast31
  b = __builtin_amdgcn_update_dpp(b, xi, 0x142, 0xf, 0xf, false);      // row_bcast15
  b = __builtin_amdgcn_update_dpp(b, xi, 0x111, 0xf, 0xf, false);      // row_shr:1
  return __builtin_bit_cast(float, b);
}

// Single block: detect mask element width, compute d_loss into out[2].
__global__ __launch_bounds__(256) void detect_dloss_kernel(
    const float* __restrict__ d, const int* __restrict__ mel_len,
    const void* __restrict__ src_mask, const void* __restrict__ pred_mask,
    int* __restrict__ flags, float* __restrict__ out)
{
  __shared__ int nzs, nzp;
  __shared__ float lb[BB];
  int tid = threadIdx.x;
  if (tid == 0) { nzs = 0; nzp = 0; }
  __syncthreads();
  const unsigned char* sm = (const unsigned char*)src_mask;
  const unsigned char* pm = (const unsigned char*)pred_mask;
  int f = 0;
  for (int i = tid; i < BB * SS; i += 256) if ((i & 3) && sm[i]) f = 1;
  if (f) atomicOr(&nzs, 1);
  f = 0;
  for (int i = tid; i < BB * TT; i += 256) if ((i & 3) && pm[i]) f = 1;
  if (f) atomicOr(&nzp, 1);
  __syncthreads();
  int isIntS = nzs ? 0 : 1;
  if (tid == 0) { flags[0] = isIntS; flags[1] = nzp ? 0 : 1; }

  int b = tid >> 4, k = tid & 15;
  float sd = 0.f, so = 0.f;
  for (int s = k; s < SS; s += 16) {
    bool m = mask_get(src_mask, b * SS + s, isIntS);
    if (!m) { sd += d[b * SS + s]; so += 1.f; }
  }
  for (int off = 8; off; off >>= 1) {
    sd += __shfl_down(sd, off, 16);
    so += __shfl_down(so, off, 16);
  }
  if (k == 0) lb[b] = fabsf((float)mel_len[b] - sd) / so;
  __syncthreads();
  if (tid == 0) {
    float s = 0.f;
    for (int i = 0; i < BB; i++) s += lb[i];
    out[2] = s / (float)BB;
  }
}

// Cost matrix (pre-scaled by SCALE), chunk-transposed skew-2 layout:
// Dsk[slot][band][chunk][lane][step_in_chunk][4 rows] halfs, where for element
// (i,j): band=i/200, l=(i%200)>>2, rr=i&3, s=j+2l, chunk=s>>3, k=s&7.
__global__ __launch_bounds__(256) void cost_kernel(
    const float* __restrict__ mel, const float* __restrict__ post,
    const float* __restrict__ target, const void* __restrict__ pred_mask,
    const int* __restrict__ flags, __half* __restrict__ Dsk, int probBase)
{
  int slot = blockIdx.z;
  int prob = probBase + slot;
  int which = prob >> 4, b = prob & 15;
  const float* X = (which ? post : mel) + (size_t)b * TT * CC;
  const float* Y = target + (size_t)b * TT * CC;
  int i0 = blockIdx.y * 64, j0 = blockIdx.x * 64;
  int isInt = flags[1];

  __shared__ __attribute__((aligned(16))) float As[16][68];
  __shared__ __attribute__((aligned(16))) float Bs[16][68];

  int tid = threadIdx.x;
  int kk = tid & 15, r4 = tid >> 4;   // staging roles
  int tx = tid & 15, ty = tid >> 4;   // compute roles
  float acc[4][4] = {};

  for (int kc = 0; kc < CC; kc += 16) {
    __syncthreads();
#pragma unroll
    for (int q = 0; q < 4; q++) {
      int i = r4 + q * 16;
      int gia = i0 + i, gib = j0 + i;
      float xs = 0.f, ys = 0.f;
      if (gia < TT) {
        float v = X[(size_t)gia * CC + kc + kk];
        if (which == 0 && mask_get(pred_mask, b * TT + gia, isInt)) v = 0.f;
        xs = 1.f / (1.f + __expf(-v));
      }
      if (gib < TT) {
        float wv = Y[(size_t)gib * CC + kc + kk];
        ys = 1.f / (1.f + __expf(-wv));
      }
      As[kk][i] = xs;
      Bs[kk][i] = ys;
    }
    __syncthreads();
#pragma unroll
    for (int k = 0; k < 16; k++) {
      float4 a4 = *(const float4*)&As[k][ty * 4];
      float4 b4 = *(const float4*)&Bs[k][tx * 4];
      float am[4] = {a4.x, a4.y, a4.z, a4.w};
      float bn[4] = {b4.x, b4.y, b4.z, b4.w};
#pragma unroll
      for (int m = 0; m < 4; m++)
#pragma unroll
        for (int n = 0; n < 4; n++) {
          float df = am[m] - bn[n];
          acc[m][n] = fmaf(df, df, acc[m][n]);
        }
    }
  }

  // epilogue: store each thread's 4x4 quad (pre-scaled) to the skewed layout
  int i4 = i0 + ty * 4;
  if (i4 < TT) {
    int band = i4 / BANDH;
    int l = (i4 % BANDH) >> 2;
    __half* base = Dsk + (size_t)slot * HALF_PER_SLOT + (size_t)band * HALF_PER_BAND;
#pragma unroll
    for (int n = 0; n < 4; n++) {
      int j = j0 + tx * 4 + n;
      if (j < TT) {
        int s = j + 2 * l;
        int ch = s >> 3, k = s & 7;
        union { __half h[4]; uint2 u; } cv;
#pragma unroll
        for (int m = 0; m < 4; m++) cv.h[m] = __float2half(acc[m][n] * SCALE);
        *(uint2*)(base + ((size_t)(ch * 50 + l)) * 32 + k * 4) = cv.u;
      }
    }
  }
}

// Wave-pipelined soft-DTW, log-free (m,s) pair state:
// value r = m - log2(s); softmin3 in pair form is A=min3(m's); m'=d+A;
// s' = su*2^(A-mu) + sl*2^(A-ml) + sd*2^(A-md). No log2 on the recursion;
// renormalize (m -= log2 s, s=1) once per 8-step chunk. Exact math (anchor
// free), exponents <= 0, s bounded within a chunk.
__global__ __launch_bounds__(256) void dtw_kernel(
    const __half* __restrict__ Dsk, float* __restrict__ out, int probBase)
{
  __shared__ float bndm[3][128];
  __shared__ float bnds[3][128];
  const int tid = threadIdx.x;
  const int w = tid >> 6, lane = tid & 63;
  const int slot = blockIdx.x;
  const int prob = probBase + slot;
  const int which = prob >> 4;
  const int lclamp = lane < 49 ? lane : 49;
  const __half* Db = Dsk + (size_t)slot * HALF_PER_SLOT + (size_t)w * HALF_PER_BAND;

  float c0m = INFV, c1m = INFV, c2m = INFV, c3m = INFV;
  float c0s = 1.f, c1s = 1.f, c2s = 1.f, c3s = 1.f;
  float pipm = INFV, pips = 1.f, prvm = INFV, prvs = 1.f;
  float rcm = INFV, rcs = 1.f, resm = INFV, ress = 1.f;
  float rbm[8], rbs[8], wrm[8], wrs[8];
#pragma unroll
  for (int k = 0; k < 8; k++) { rbm[k] = INFV; rbs[k] = 1.f; wrm[k] = INFV; wrs[k] = 1.f; }

  uint4 a0, a1, a2, a3, b0, b1, b2, b3;

#define PRE(P0, P1, P2, P3, LCN) do { if ((LCN) < NLCB) {                     \
    const uint4* p_ = (const uint4*)(Db + ((size_t)(LCN) * 50 + lclamp) * 32);\
    P0 = p_[0]; P1 = p_[1]; P2 = p_[2]; P3 = p_[3]; } } while (0)

#define RINGLOAD do { if (w) {                                                \
    const float4* rpm_ = (const float4*)&bndm[w - 1][s0 & 127];               \
    const float4* rps_ = (const float4*)&bnds[w - 1][s0 & 127];               \
    float4 ra_ = rpm_[0], rc_ = rpm_[1];                                      \
    rbm[0] = ra_.x; rbm[1] = ra_.y; rbm[2] = ra_.z; rbm[3] = ra_.w;           \
    rbm[4] = rc_.x; rbm[5] = rc_.y; rbm[6] = rc_.z; rbm[7] = rc_.w;           \
    float4 sa_ = rps_[0], sc_ = rps_[1];                                      \
    rbs[0] = sa_.x; rbs[1] = sa_.y; rbs[2] = sa_.z; rbs[3] = sa_.w;           \
    rbs[4] = sc_.x; rbs[5] = sc_.y; rbs[6] = sc_.z; rbs[7] = sc_.w; } } while (0)

#define DO_STEP(K, LOU, HIU) do {                                             \
    const int s_ = s0 + (K);                                                  \
    float nxtm_ = shift_up1(c3m);                                             \
    float nxts_ = shift_up1(c3s);                                             \
    unsigned lou_ = (LOU), hiu_ = (HIU);                                      \
    float2 f01 = __half22float2(*(const __half2*)&lou_);                      \
    float2 f23 = __half22float2(*(const __half2*)&hiu_);                      \
    float upm_ = pipm, ups_ = pips, dgm_ = prvm, dgs_ = prvs;                 \
    if (w == 0) { if (lane == 0) { upm_ = INFV; ups_ = 1.f;                   \
        dgm_ = (s_ == 0) ? 0.0f : INFV; dgs_ = 1.f; } }                       \
    else if (lane == 0) { upm_ = rbm[(K)]; ups_ = rbs[(K)];                   \
        dgm_ = ((K) == 0) ? rcm : rbm[(K) == 0 ? 0 : (K) - 1];                \
        dgs_ = ((K) == 0) ? rcs : rbs[(K) == 0 ? 0 : (K) - 1]; }              \
    float o0m = c0m, o0s = c0s, o1m = c1m, o1s = c1s, o2m = c2m, o2s = c2s;   \
    float A0 = fmin3(upm_, c0m, dgm_);                                        \
    float n0m = f01.x + A0;                                                   \
    float n0s = fmaf(ups_, fexp2(A0 - upm_),                                  \
                fmaf(c0s, fexp2(A0 - c0m), dgs_ * fexp2(A0 - dgm_)));         \
    float A1 = fmin3(n0m, c1m, o0m);                                          \
    float n1m = f01.y + A1;                                                   \
    float n1s = fmaf(n0s, fexp2(A1 - n0m),                                    \
                fmaf(c1s, fexp2(A1 - c1m), o0s * fexp2(A1 - o0m)));           \
    float A2 = fmin3(n1m, c2m, o1m);                                          \
    float n2m = f23.x + A2;                                                   \
    float n2s = fmaf(n1s, fexp2(A2 - n1m),                                    \
                fmaf(c2s, fexp2(A2 - c2m), o1s * fexp2(A2 - o1m)));           \
    float A3 = fmin3(n2m, c3m, o2m);                                          \
    float n3m = f23.y + A3;                                                   \
    float n3s = fmaf(n2s, fexp2(A3 - n2m),                                    \
                fmaf(c3s, fexp2(A3 - c3m), o2s * fexp2(A3 - o2m)));           \
    int j_ = s_ - 2 * lane;                                                   \
    bool act_ = (lane < 50) && ((unsigned)j_ < 800u);                         \
    c0m = act_ ? n0m : INFV; c0s = act_ ? n0s : 1.f;                          \
    c1m = act_ ? n1m : INFV; c1s = act_ ? n1s : 1.f;                          \
    c2m = act_ ? n2m : INFV; c2s = act_ ? n2s : 1.f;                          \
    c3m = act_ ? n3m : INFV; c3s = act_ ? n3s : 1.f;                          \
    wrm[(K)] = c3m; wrs[(K)] = c3s;                                           \
    if (s_ == 897) { resm = c3m; ress = c3s; }                                \
    prvm = pipm; prvs = pips; pipm = nxtm_; pips = nxts_;                     \
  } while (0)

#define STEP8(Q0, Q1, Q2, Q3) do {                                            \
    DO_STEP(0, Q0.x, Q0.y); DO_STEP(1, Q0.z, Q0.w);                           \
    DO_STEP(2, Q1.x, Q1.y); DO_STEP(3, Q1.z, Q1.w);                           \
    DO_STEP(4, Q2.x, Q2.y); DO_STEP(5, Q2.z, Q2.w);                           \
    DO_STEP(6, Q3.x, Q3.y); DO_STEP(7, Q3.z, Q3.w); } while (0)

  // prologue: every wave loads its local chunk 0
  PRE(a0, a1, a2, a3, 0);
  __syncthreads();

  for (int G = 0; G < NGC; ++G) {
    const int lc = G - LAGCH * w;
    if (lc >= 0 && lc < NLCB) {
      const int s0 = lc << 3;
      if ((lc & 1) == 0) {
        PRE(b0, b1, b2, b3, lc + 1);
        RINGLOAD;
        STEP8(a0, a1, a2, a3);
      } else {
        PRE(a0, a1, a2, a3, lc + 1);
        RINGLOAD;
        STEP8(b0, b1, b2, b3);
      }
      if (w < 3 && lane == 49) {
#pragma unroll
        for (int k = 0; k < 8; k++) {
          int j = s0 + k - 98;
          if ((unsigned)j < 800u) { bndm[w][j & 127] = wrm[k]; bnds[w][j & 127] = wrs[k]; }
        }
      }
      rcm = rbm[7]; rcs = rbs[7];
      // per-chunk renormalization: keep s bounded (representation-invariant)
      c0m -= flog2(c0s); c0s = 1.f;
      c1m -= flog2(c1s); c1s = 1.f;
      c2m -= flog2(c2s); c2s = 1.f;
      c3m -= flog2(c3s); c3s = 1.f;
    }
    __syncthreads();
  }

  // res = resm - log2(ress), pre-scaled; unscale and apply 0.001/16.
  if (w == 3 && lane == 49)
    atomicAdd(&out[which], (resm - flog2(ress)) * 4.3321699e-6f);

#undef PRE
#undef RINGLOAD
#undef DO_STEP
#undef STEP8
}

extern "C" void kernel_launch(void* const* d_in, const int* in_sizes, int n_in,
                              void* d_out, int out_size, void* d_ws, size_t ws_size,
                              hipStream_t stream) {
  const float* d         = (const float*)d_in[0];
  const int*   mel_len   = (const int*)d_in[1];
  const float* mel       = (const float*)d_in[2];
  const float* post      = (const float*)d_in[3];
  const float* target    = (const float*)d_in[4];
  const void*  src_mask  = d_in[5];
  const void*  pred_mask = d_in[6];
  float* out = (float*)d_out;

  int* flags = (int*)d_ws;
  __half* Dsk = (__half*)((char*)d_ws + 256);
  size_t per = (size_t)HALF_PER_SLOT * sizeof(__half);  // 1.446 MB per problem
  int slots = 0;
  if (ws_size > 256) slots = (int)((ws_size - 256) / per);
  if (slots > 32) slots = 32;

  (void)hipMemsetAsync(d_out, 0, 3 * sizeof(float), stream);
  detect_dloss_kernel<<<1, 256, 0, stream>>>(d, mel_len, src_mask, pred_mask, flags, out);
  if (slots < 1) return;

  for (int base = 0; base < 32; base += slots) {
    int g = (32 - base < slots) ? (32 - base) : slots;
    cost_kernel<<<dim3(13, 13, g), 256, 0, stream>>>(mel, post, target, pred_mask,
                                                     flags, Dsk, base);
    dtw_kernel<<<g, 256, 0, stream>>>(Dsk, out, base);
  }
}

// Round 10
// 433.331 us; speedup vs baseline: 1.2526x; 1.2526x over previous
//
#include <hip/hip_runtime.h>
#include <hip/hip_fp16.h>

#define TT 800
#define CC 80
#define BB 16
#define SS 128
#define INFV 1e9f
#define NLCB 113          // local chunks per band (904 steps / 8)
#define LAGCH 14          // chunk lag between bands (112 steps >= 98 + 8 + margin)
#define NGC 155           // 113 + 3*14
#define BANDH 200         // rows per band (4 bands x 200 = 800)
#define HALF_PER_BAND (113*50*32)     // 180800
#define HALF_PER_SLOT (4*113*50*32)   // 723200
#define SCALE 14.426950408889634f     // (1/gamma)*log2(e), gamma=0.1
#define SIG_ELEMS (BB*TT*CC)          // 1,024,000 per array
#define SIG_BYTES (3*SIG_ELEMS*2)     // 6,144,000

// Bool masks may arrive as 1-byte numpy bools or int32 — detected at runtime.
__device__ inline bool mask_get(const void* p, int idx, int isInt) {
  if (isInt) return ((const int*)p)[idx] != 0;
  return ((const unsigned char*)p)[idx] != 0;
}

__device__ __forceinline__ float fexp2(float x) {
#if __has_builtin(__builtin_amdgcn_exp2f)
  return __builtin_amdgcn_exp2f(x);
#else
  return __expf(x * 0.6931471805599453f);
#endif
}
__device__ __forceinline__ float flog2(float x) {
#if __has_builtin(__builtin_amdgcn_logf)
  return __builtin_amdgcn_logf(x);
#else
  return __logf(x) * 1.4426950408889634f;
#endif
}
__device__ __forceinline__ float fmed3(float a, float b, float c) {
#if __has_builtin(__builtin_amdgcn_fmed3f)
  return __builtin_amdgcn_fmed3f(a, b, c);
#else
  return fmaxf(fminf(a, b), fminf(fmaxf(a, b), c));
#endif
}
__device__ __forceinline__ float fmin3(float a, float b, float c) {
  return fminf(fminf(a, b), c);
}

// Wave-wide shift-up-by-1 on the VALU pipe (no LDS): DPP compose.
__device__ __forceinline__ float shift_up1(float x) {
  int xi = __builtin_bit_cast(int, x);
  int b = __builtin_amdgcn_update_dpp(xi, xi, 0x143, 0xf, 0xf, false); // row_bcast31
  b = __builtin_amdgcn_update_dpp(b, xi, 0x142, 0xf, 0xf, false);      // row_bcast15
  b = __builtin_amdgcn_update_dpp(b, xi, 0x111, 0xf, 0xf, false);      // row_shr:1
  return __builtin_bit_cast(float, b);
}

// Pre-scaled softmin3 (inputs are R*SCALE, d is D*SCALE):
// r' = d' + mn' - log2(1 + 2^(mn'-md') + 2^(mn'-mx'))
__device__ __forceinline__ float cellf(float d, float a, float b, float c) {
  float mn = fminf(fminf(a, b), c);
  float mx = fmaxf(fmaxf(a, b), c);
  float md = fmed3(a, b, c);
  float e1 = fexp2(mn - md);
  float e2 = fexp2(mn - mx);
  float s = 1.0f + e1 + e2;
  return (d + mn) - flog2(s);
}

// Single block: detect mask element width, compute d_loss into out[2].
__global__ __launch_bounds__(256) void detect_dloss_kernel(
    const float* __restrict__ d, const int* __restrict__ mel_len,
    const void* __restrict__ src_mask, const void* __restrict__ pred_mask,
    int* __restrict__ flags, float* __restrict__ out)
{
  __shared__ int nzs, nzp;
  __shared__ float lb[BB];
  int tid = threadIdx.x;
  if (tid == 0) { nzs = 0; nzp = 0; }
  __syncthreads();
  const unsigned char* sm = (const unsigned char*)src_mask;
  const unsigned char* pm = (const unsigned char*)pred_mask;
  int f = 0;
  for (int i = tid; i < BB * SS; i += 256) if ((i & 3) && sm[i]) f = 1;
  if (f) atomicOr(&nzs, 1);
  f = 0;
  for (int i = tid; i < BB * TT; i += 256) if ((i & 3) && pm[i]) f = 1;
  if (f) atomicOr(&nzp, 1);
  __syncthreads();
  int isIntS = nzs ? 0 : 1;
  if (tid == 0) { flags[0] = isIntS; flags[1] = nzp ? 0 : 1; }

  int b = tid >> 4, k = tid & 15;
  float sd = 0.f, so = 0.f;
  for (int s = k; s < SS; s += 16) {
    bool m = mask_get(src_mask, b * SS + s, isIntS);
    if (!m) { sd += d[b * SS + s]; so += 1.f; }
  }
  for (int off = 8; off; off >>= 1) {
    sd += __shfl_down(sd, off, 16);
    so += __shfl_down(so, off, 16);
  }
  if (k == 0) lb[b] = fabsf((float)mel_len[b] - sd) / so;
  __syncthreads();
  if (tid == 0) {
    float s = 0.f;
    for (int i = 0; i < BB; i++) s += lb[i];
    out[2] = s / (float)BB;
  }
}

// Sigmoid pre-pass: sig[0]=sigmoid(masked mel), sig[1]=sigmoid(post),
// sig[2]=sigmoid(target), each [16][800][80] fp16. 8 elems/thread, vectorized.
__global__ __launch_bounds__(256) void sig_kernel(
    const float* __restrict__ mel, const float* __restrict__ post,
    const float* __restrict__ target, const void* __restrict__ pred_mask,
    const int* __restrict__ flags, __half* __restrict__ sig)
{
  int arr = blockIdx.y;
  const float* src = arr == 0 ? mel : (arr == 1 ? post : target);
  __half* dst = sig + (size_t)arr * SIG_ELEMS;
  int pack = blockIdx.x * 256 + threadIdx.x;
  if (pack >= SIG_ELEMS / 8) return;
  size_t e0 = (size_t)pack * 8;                 // 80 % 8 == 0: pack within one t
  float4 v0 = *(const float4*)(src + e0);
  float4 v1 = *(const float4*)(src + e0 + 4);
  if (arr == 0) {
    int bt = (int)(e0 / CC);                    // b*800 + t
    if (mask_get(pred_mask, bt, flags[1])) {
      v0 = make_float4(0.f, 0.f, 0.f, 0.f);
      v1 = make_float4(0.f, 0.f, 0.f, 0.f);
    }
  }
  float f[8] = {v0.x, v0.y, v0.z, v0.w, v1.x, v1.y, v1.z, v1.w};
  union { __half h[8]; uint4 u; } o;
#pragma unroll
  for (int i = 0; i < 8; i++) o.h[i] = __float2half(1.f / (1.f + __expf(-f[i])));
  *(uint4*)(dst + e0) = o.u;
}

// Cost matrix (pre-scaled by SCALE), chunk-transposed skew-2 layout:
// Dsk[slot][band][chunk][lane][step_in_chunk][4 rows] halfs, where for element
// (i,j): band=i/200, l=(i%200)>>2, rr=i&3, s=j+2l, chunk=s>>3, k=s&7.
// Inputs are the pre-sigmoided fp16 arrays (no exp, no mask here).
__global__ __launch_bounds__(256) void cost_kernel(
    const __half* __restrict__ sig, __half* __restrict__ Dsk, int probBase)
{
  int slot = blockIdx.z;
  int prob = probBase + slot;
  int which = prob >> 4, b = prob & 15;
  const __half* X = sig + (size_t)which * SIG_ELEMS + (size_t)b * TT * CC;
  const __half* Y = sig + (size_t)2 * SIG_ELEMS + (size_t)b * TT * CC;
  int i0 = blockIdx.y * 64, j0 = blockIdx.x * 64;

  __shared__ __attribute__((aligned(16))) float As[16][68];
  __shared__ __attribute__((aligned(16))) float Bs[16][68];

  int tid = threadIdx.x;
  int kk = tid & 15, r4 = tid >> 4;   // staging roles
  int tx = tid & 15, ty = tid >> 4;   // compute roles
  float acc[4][4] = {};

  for (int kc = 0; kc < CC; kc += 16) {
    __syncthreads();
#pragma unroll
    for (int q = 0; q < 4; q++) {
      int i = r4 + q * 16;
      int gia = i0 + i, gib = j0 + i;
      As[kk][i] = (gia < TT) ? __half2float(X[(size_t)gia * CC + kc + kk]) : 0.f;
      Bs[kk][i] = (gib < TT) ? __half2float(Y[(size_t)gib * CC + kc + kk]) : 0.f;
    }
    __syncthreads();
#pragma unroll
    for (int k = 0; k < 16; k++) {
      float4 a4 = *(const float4*)&As[k][ty * 4];
      float4 b4 = *(const float4*)&Bs[k][tx * 4];
      float am[4] = {a4.x, a4.y, a4.z, a4.w};
      float bn[4] = {b4.x, b4.y, b4.z, b4.w};
#pragma unroll
      for (int m = 0; m < 4; m++)
#pragma unroll
        for (int n = 0; n < 4; n++) {
          float df = am[m] - bn[n];
          acc[m][n] = fmaf(df, df, acc[m][n]);
        }
    }
  }

  // epilogue: store each thread's 4x4 quad (pre-scaled) to the skewed layout
  int i4 = i0 + ty * 4;
  if (i4 < TT) {
    int band = i4 / BANDH;
    int l = (i4 % BANDH) >> 2;
    __half* base = Dsk + (size_t)slot * HALF_PER_SLOT + (size_t)band * HALF_PER_BAND;
#pragma unroll
    for (int n = 0; n < 4; n++) {
      int j = j0 + tx * 4 + n;
      if (j < TT) {
        int s = j + 2 * l;
        int ch = s >> 3, k = s & 7;
        union { __half h[4]; uint2 u; } cv;
#pragma unroll
        for (int m = 0; m < 4; m++) cv.h[m] = __float2half(acc[m][n] * SCALE);
        *(uint2*)(base + ((size_t)(ch * 50 + l)) * 32 + k * 4) = cv.u;
      }
    }
  }
}

// Wave-pipelined soft-DTW (pre-scaled, anchored (m,s) form): 4 waves = 4 bands
// of 200 rows (lanes 0..49, 4 rows each), skew-2. Per-step cross-lane transfer
// is a 3-op DPP compose — zero DS ops per step. [frozen at round-8 best]
__global__ __launch_bounds__(256) void dtw_kernel(
    const __half* __restrict__ Dsk, float* __restrict__ out, int probBase)
{
  __shared__ float bnd[3][128];
  const int tid = threadIdx.x;
  const int w = tid >> 6, lane = tid & 63;
  const int slot = blockIdx.x;
  const int prob = probBase + slot;
  const int which = prob >> 4;
  const int lclamp = lane < 49 ? lane : 49;
  const __half* Db = Dsk + (size_t)slot * HALF_PER_SLOT + (size_t)w * HALF_PER_BAND;

  float cur0 = INFV, cur1 = INFV, cur2 = INFV, cur3 = INFV;
  float up_pipe = INFV, up_prev = INFV, rcarry = INFV, res = 0.f;
  float rbv[8], wrv[8];
#pragma unroll
  for (int k = 0; k < 8; k++) { rbv[k] = INFV; wrv[k] = INFV; }

  uint4 a0, a1, a2, a3, b0, b1, b2, b3;

#define PRE(P0, P1, P2, P3, LCN) do { if ((LCN) < NLCB) {                     \
    const uint4* p_ = (const uint4*)(Db + ((size_t)(LCN) * 50 + lclamp) * 32);\
    P0 = p_[0]; P1 = p_[1]; P2 = p_[2]; P3 = p_[3]; } } while (0)

#define RINGLOAD do { if (w) {                                                \
    const float4* rp_ = (const float4*)&bnd[w - 1][s0 & 127];                 \
    float4 ra_ = rp_[0], rc_ = rp_[1];                                        \
    rbv[0] = ra_.x; rbv[1] = ra_.y; rbv[2] = ra_.z; rbv[3] = ra_.w;           \
    rbv[4] = rc_.x; rbv[5] = rc_.y; rbv[6] = rc_.z; rbv[7] = rc_.w; } } while (0)

#define DO_STEP(K, LOU, HIU) do {                                             \
    const int s_ = s0 + (K);                                                  \
    float nxt_ = shift_up1(cur3);                                             \
    unsigned lou_ = (LOU), hiu_ = (HIU);                                      \
    float2 f01 = __half22float2(*(const __half2*)&lou_);                      \
    float2 f23 = __half22float2(*(const __half2*)&hiu_);                      \
    float up_ = up_pipe, dg_ = up_prev;                                       \
    if (w == 0) { if (lane == 0) { up_ = INFV; dg_ = (s_ == 0) ? 0.0f : INFV; } } \
    else if (lane == 0) { up_ = rbv[(K)]; dg_ = ((K) == 0) ? rcarry : rbv[(K) == 0 ? 0 : (K) - 1]; } \
    float oc0 = cur0, oc1 = cur1, oc2 = cur2;                                 \
    float A0 = fmin3(up_, cur0, dg_);                                         \
    float m0 = f01.x + A0;                                                    \
    float sv0 = fexp2(A0 - up_) + fexp2(A0 - cur0) + fexp2(A0 - dg_);         \
    float A1 = fmin3(m0, cur1, oc0);                                          \
    float m1 = f01.y + A1;                                                    \
    float sv1 = fmaf(sv0, fexp2(A1 - m0), fexp2(A1 - cur1) + fexp2(A1 - oc0));\
    float A2 = fmin3(m1, cur2, oc1);                                          \
    float m2 = f23.x + A2;                                                    \
    float sv2 = fmaf(sv1, fexp2(A2 - m1), fexp2(A2 - cur2) + fexp2(A2 - oc1));\
    float A3 = fmin3(m2, cur3, oc2);                                          \
    float m3 = f23.y + A3;                                                    \
    float sv3 = fmaf(sv2, fexp2(A3 - m2), fexp2(A3 - cur3) + fexp2(A3 - oc2));\
    float r0 = m0 - flog2(sv0);                                               \
    float r1 = m1 - flog2(sv1);                                               \
    float r2 = m2 - flog2(sv2);                                               \
    float r3 = m3 - flog2(sv3);                                               \
    int j_ = s_ - 2 * lane;                                                   \
    bool act_ = (lane < 50) && ((unsigned)j_ < 800u);                         \
    cur0 = act_ ? r0 : INFV; cur1 = act_ ? r1 : INFV;                         \
    cur2 = act_ ? r2 : INFV; cur3 = act_ ? r3 : INFV;                         \
    wrv[(K)] = cur3;                                                          \
    if (s_ == 897) res = cur3;                                                \
    up_prev = up_pipe; up_pipe = nxt_;                                        \
  } while (0)

#define STEP8(Q0, Q1, Q2, Q3) do {                                            \
    DO_STEP(0, Q0.x, Q0.y); DO_STEP(1, Q0.z, Q0.w);                           \
    DO_STEP(2, Q1.x, Q1.y); DO_STEP(3, Q1.z, Q1.w);                           \
    DO_STEP(4, Q2.x, Q2.y); DO_STEP(5, Q2.z, Q2.w);                           \
    DO_STEP(6, Q3.x, Q3.y); DO_STEP(7, Q3.z, Q3.w); } while (0)

  // prologue: every wave loads its local chunk 0
  PRE(a0, a1, a2, a3, 0);
  __syncthreads();

  for (int G = 0; G < NGC; ++G) {
    const int lc = G - LAGCH * w;
    if (lc >= 0 && lc < NLCB) {
      const int s0 = lc << 3;
      if ((lc & 1) == 0) {
        PRE(b0, b1, b2, b3, lc + 1);
        RINGLOAD;
        STEP8(a0, a1, a2, a3);
      } else {
        PRE(a0, a1, a2, a3, lc + 1);
        RINGLOAD;
        STEP8(b0, b1, b2, b3);
      }
      if (w < 3 && lane == 49) {
#pragma unroll
        for (int k = 0; k < 8; k++) {
          int j = s0 + k - 98;
          if ((unsigned)j < 800u) bnd[w][j & 127] = wrv[k];
        }
      }
      rcarry = rbv[7];
    }
    __syncthreads();
  }

  // res is pre-scaled; unscale (1/SCALE) and apply 0.001/16 in one constant.
  if (w == 3 && lane == 49) atomicAdd(&out[which], res * 4.3321699e-6f);

#undef PRE
#undef RINGLOAD
#undef DO_STEP
#undef STEP8
}

extern "C" void kernel_launch(void* const* d_in, const int* in_sizes, int n_in,
                              void* d_out, int out_size, void* d_ws, size_t ws_size,
                              hipStream_t stream) {
  const float* d         = (const float*)d_in[0];
  const int*   mel_len   = (const int*)d_in[1];
  const float* mel       = (const float*)d_in[2];
  const float* post      = (const float*)d_in[3];
  const float* target    = (const float*)d_in[4];
  const void*  src_mask  = d_in[5];
  const void*  pred_mask = d_in[6];
  float* out = (float*)d_out;

  int* flags = (int*)d_ws;
  __half* sig = (__half*)((char*)d_ws + 256);
  __half* Dsk = (__half*)((char*)d_ws + 256 + SIG_BYTES);   // 16B-aligned
  size_t per = (size_t)HALF_PER_SLOT * sizeof(__half);      // 1.446 MB per problem
  size_t hdr = 256 + (size_t)SIG_BYTES;
  int slots = 0;
  if (ws_size > hdr) slots = (int)((ws_size - hdr) / per);
  if (slots > 32) slots = 32;

  (void)hipMemsetAsync(d_out, 0, 3 * sizeof(float), stream);
  detect_dloss_kernel<<<1, 256, 0, stream>>>(d, mel_len, src_mask, pred_mask, flags, out);
  if (slots < 1) return;
  sig_kernel<<<dim3(500, 3), 256, 0, stream>>>(mel, post, target, pred_mask, flags, sig);

  for (int base = 0; base < 32; base += slots) {
    int g = (32 - base < slots) ? (32 - base) : slots;
    cost_kernel<<<dim3(13, 13, g), 256, 0, stream>>>(sig, Dsk, base);
    dtw_kernel<<<g, 256, 0, stream>>>(Dsk, out, base);
  }
}

// Round 12
// 350.470 us; speedup vs baseline: 1.5487x; 1.2364x over previous
//
#include <hip/hip_runtime.h>
#include <hip/hip_fp16.h>

#define TT 800
#define CC 80
#define BB 16
#define SS 128
#define INFV 1e9f
#define NLCB 107          // local chunks per band (856 steps / 8; max s = 848)
#define LAGCH 8           // chunk lag between bands (64 steps >= 49 + 8 + margin)
#define NGC 131           // 107 + 3*8
#define BANDH 200         // rows per band (4 bands x 200 = 800)
#define HALF_PER_BAND (107*50*32)     // 171200
#define HALF_PER_SLOT (4*107*50*32)   // 684800
#define SCALE 14.426950408889634f     // (1/gamma)*log2(e), gamma=0.1
#define SIG_ELEMS (BB*TT*CC)          // 1,024,000 per array
#define SIG_BYTES (3*SIG_ELEMS*2)     // 6,144,000

// Bool masks may arrive as 1-byte numpy bools or int32 — detected at runtime.
__device__ inline bool mask_get(const void* p, int idx, int isInt) {
  if (isInt) return ((const int*)p)[idx] != 0;
  return ((const unsigned char*)p)[idx] != 0;
}

__device__ __forceinline__ float fexp2(float x) {
#if __has_builtin(__builtin_amdgcn_exp2f)
  return __builtin_amdgcn_exp2f(x);
#else
  return __expf(x * 0.6931471805599453f);
#endif
}
__device__ __forceinline__ float flog2(float x) {
#if __has_builtin(__builtin_amdgcn_logf)
  return __builtin_amdgcn_logf(x);
#else
  return __logf(x) * 1.4426950408889634f;
#endif
}
__device__ __forceinline__ float fmin3(float a, float b, float c) {
  return fminf(fminf(a, b), c);
}

// Wave-wide shift-up-by-1 on the VALU pipe (no LDS): DPP compose.
__device__ __forceinline__ float shift_up1(float x) {
  int xi = __builtin_bit_cast(int, x);
  int b = __builtin_amdgcn_update_dpp(xi, xi, 0x143, 0xf, 0xf, false); // row_bcast31
  b = __builtin_amdgcn_update_dpp(b, xi, 0x142, 0xf, 0xf, false);      // row_bcast15
  b = __builtin_amdgcn_update_dpp(b, xi, 0x111, 0xf, 0xf, false);      // row_shr:1
  return __builtin_bit_cast(float, b);
}

// Single block: detect mask element width, compute d_loss into out[2].
__global__ __launch_bounds__(256) void detect_dloss_kernel(
    const float* __restrict__ d, const int* __restrict__ mel_len,
    const void* __restrict__ src_mask, const void* __restrict__ pred_mask,
    int* __restrict__ flags, float* __restrict__ out)
{
  __shared__ int nzs, nzp;
  __shared__ float lb[BB];
  int tid = threadIdx.x;
  if (tid == 0) { nzs = 0; nzp = 0; }
  __syncthreads();
  const unsigned char* sm = (const unsigned char*)src_mask;
  const unsigned char* pm = (const unsigned char*)pred_mask;
  int f = 0;
  for (int i = tid; i < BB * SS; i += 256) if ((i & 3) && sm[i]) f = 1;
  if (f) atomicOr(&nzs, 1);
  f = 0;
  for (int i = tid; i < BB * TT; i += 256) if ((i & 3) && pm[i]) f = 1;
  if (f) atomicOr(&nzp, 1);
  __syncthreads();
  int isIntS = nzs ? 0 : 1;
  if (tid == 0) { flags[0] = isIntS; flags[1] = nzp ? 0 : 1; }

  int b = tid >> 4, k = tid & 15;
  float sd = 0.f, so = 0.f;
  for (int s = k; s < SS; s += 16) {
    bool m = mask_get(src_mask, b * SS + s, isIntS);
    if (!m) { sd += d[b * SS + s]; so += 1.f; }
  }
  for (int off = 8; off; off >>= 1) {
    sd += __shfl_down(sd, off, 16);
    so += __shfl_down(so, off, 16);
  }
  if (k == 0) lb[b] = fabsf((float)mel_len[b] - sd) / so;
  __syncthreads();
  if (tid == 0) {
    float s = 0.f;
    for (int i = 0; i < BB; i++) s += lb[i];
    out[2] = s / (float)BB;
  }
}

// Sigmoid pre-pass: sig[0]=sigmoid(masked mel), sig[1]=sigmoid(post),
// sig[2]=sigmoid(target), each [16][800][80] fp16. 8 elems/thread, vectorized.
__global__ __launch_bounds__(256) void sig_kernel(
    const float* __restrict__ mel, const float* __restrict__ post,
    const float* __restrict__ target, const void* __restrict__ pred_mask,
    const int* __restrict__ flags, __half* __restrict__ sig)
{
  int arr = blockIdx.y;
  const float* src = arr == 0 ? mel : (arr == 1 ? post : target);
  __half* dst = sig + (size_t)arr * SIG_ELEMS;
  int pack = blockIdx.x * 256 + threadIdx.x;
  if (pack >= SIG_ELEMS / 8) return;
  size_t e0 = (size_t)pack * 8;
  float4 v0 = *(const float4*)(src + e0);
  float4 v1 = *(const float4*)(src + e0 + 4);
  if (arr == 0) {
    int bt = (int)(e0 / CC);
    if (mask_get(pred_mask, bt, flags[1])) {
      v0 = make_float4(0.f, 0.f, 0.f, 0.f);
      v1 = make_float4(0.f, 0.f, 0.f, 0.f);
    }
  }
  float f[8] = {v0.x, v0.y, v0.z, v0.w, v1.x, v1.y, v1.z, v1.w};
  union { __half h[8]; uint4 u; } o;
#pragma unroll
  for (int i = 0; i < 8; i++) o.h[i] = __float2half(1.f / (1.f + __expf(-f[i])));
  *(uint4*)(dst + e0) = o.u;
}

// Cost matrix (pre-scaled by SCALE), chunk-transposed skew-1 layout:
// Dsk[slot][band][chunk][lane][step8][4rows] halfs; for element (i,j):
// band=i/200, l=(i%200)>>2, rr=i&3, s=j+l, ch=s>>3, k=s&7.
// v2: vectorized uint2 staging + register-prefetch double buffer.
__global__ __launch_bounds__(256) void cost_kernel(
    const __half* __restrict__ sig, __half* __restrict__ Dsk, int probBase)
{
  int slot = blockIdx.z;
  int prob = probBase + slot;
  int which = prob >> 4, b = prob & 15;
  const __half* X = sig + (size_t)which * SIG_ELEMS + (size_t)b * TT * CC;
  const __half* Y = sig + (size_t)2 * SIG_ELEMS + (size_t)b * TT * CC;
  int i0 = blockIdx.y * 64, j0 = blockIdx.x * 64;

  __shared__ __attribute__((aligned(16))) float As[16][68];
  __shared__ __attribute__((aligned(16))) float Bs[16][68];

  int tid = threadIdx.x;
  int sr = tid >> 2, sc = (tid & 3) << 2;   // staging: row, ch-quad
  int tx = tid & 15, ty = tid >> 4;         // compute roles
  int gia = i0 + sr, gib = j0 + sr;
  bool iok = gia < TT, jok = gib < TT;
  float acc[4][4] = {};
  union { uint2 u; __half h[4]; } px, py, npx, npy;
  px.u = make_uint2(0, 0); py.u = make_uint2(0, 0);
  if (iok) px.u = *(const uint2*)(X + (size_t)gia * CC + sc);
  if (jok) py.u = *(const uint2*)(Y + (size_t)gib * CC + sc);

  for (int kc = 0; kc < CC; kc += 16) {
    npx.u = make_uint2(0, 0); npy.u = make_uint2(0, 0);
    if (kc + 16 < CC) {   // prefetch next chunk before barrier (latency hidden)
      if (iok) npx.u = *(const uint2*)(X + (size_t)gia * CC + kc + 16 + sc);
      if (jok) npy.u = *(const uint2*)(Y + (size_t)gib * CC + kc + 16 + sc);
    }
    __syncthreads();   // previous compute done reading LDS
#pragma unroll
    for (int cc = 0; cc < 4; cc++) {
      As[sc + cc][sr] = __half2float(px.h[cc]);
      Bs[sc + cc][sr] = __half2float(py.h[cc]);
    }
    __syncthreads();
#pragma unroll
    for (int k = 0; k < 16; k++) {
      float4 a4 = *(const float4*)&As[k][ty * 4];
      float4 b4 = *(const float4*)&Bs[k][tx * 4];
      float am[4] = {a4.x, a4.y, a4.z, a4.w};
      float bn[4] = {b4.x, b4.y, b4.z, b4.w};
#pragma unroll
      for (int m = 0; m < 4; m++)
#pragma unroll
        for (int n = 0; n < 4; n++) {
          float df = am[m] - bn[n];
          acc[m][n] = fmaf(df, df, acc[m][n]);
        }
    }
    px.u = npx.u; py.u = npy.u;
  }

  // epilogue: store each thread's 4x4 quad (pre-scaled) to the skew-1 layout
  int i4 = i0 + ty * 4;
  if (i4 < TT) {
    int band = i4 / BANDH;
    int l = (i4 % BANDH) >> 2;
    __half* base = Dsk + (size_t)slot * HALF_PER_SLOT + (size_t)band * HALF_PER_BAND;
#pragma unroll
    for (int n = 0; n < 4; n++) {
      int j = j0 + tx * 4 + n;
      if (j < TT) {
        int s = j + l;
        int ch = s >> 3, k = s & 7;
        union { __half h[4]; uint2 u; } cv;
#pragma unroll
        for (int m = 0; m < 4; m++) cv.h[m] = __float2half(acc[m][n] * SCALE);
        *(uint2*)(base + ((size_t)(ch * 50 + l)) * 32 + k * 4) = cv.u;
      }
    }
  }
}

// Wave-pipelined soft-DTW: 4 waves = 4 bands of 200 rows (lanes 0..49, 4 rows
// each), skew-1 (lane l at col j = s-l). Phasing: lane l-1 is ONE column ahead,
// so the DPP shuffle issued at step s delivers R[4l-1][j] (up for THIS step)
// and the previous step's shuffle is diag — consume-immediately wiring (r6's
// verified pattern), NOT the skew-2 one-step pipeline. Band lag 49 -> wall
// 1048 steps vs 1240.
__global__ __launch_bounds__(256) void dtw_kernel(
    const __half* __restrict__ Dsk, float* __restrict__ out, int probBase)
{
  __shared__ float bnd[3][128];
  const int tid = threadIdx.x;
  const int w = tid >> 6, lane = tid & 63;
  const int slot = blockIdx.x;
  const int prob = probBase + slot;
  const int which = prob >> 4;
  const int lclamp = lane < 49 ? lane : 49;
  const __half* Db = Dsk + (size_t)slot * HALF_PER_SLOT + (size_t)w * HALF_PER_BAND;

  float cur0 = INFV, cur1 = INFV, cur2 = INFV, cur3 = INFV;
  float up_pipe = INFV, rcarry = INFV, res = 0.f;
  float rbv[8], wrv[8];
#pragma unroll
  for (int k = 0; k < 8; k++) { rbv[k] = INFV; wrv[k] = INFV; }

  uint4 a0, a1, a2, a3, b0, b1, b2, b3;

#define PRE(P0, P1, P2, P3, LCN) do { if ((LCN) < NLCB) {                     \
    const uint4* p_ = (const uint4*)(Db + ((size_t)(LCN) * 50 + lclamp) * 32);\
    P0 = p_[0]; P1 = p_[1]; P2 = p_[2]; P3 = p_[3]; } } while (0)

#define RINGLOAD do { if (w) {                                                \
    const float4* rp_ = (const float4*)&bnd[w - 1][s0 & 127];                 \
    float4 ra_ = rp_[0], rc_ = rp_[1];                                        \
    rbv[0] = ra_.x; rbv[1] = ra_.y; rbv[2] = ra_.z; rbv[3] = ra_.w;           \
    rbv[4] = rc_.x; rbv[5] = rc_.y; rbv[6] = rc_.z; rbv[7] = rc_.w; } } while (0)

#define DO_STEP(K, LOU, HIU) do {                                             \
    const int s_ = s0 + (K);                                                  \
    float nxt_ = shift_up1(cur3);   /* R[4l-1][j] this step (junk lane0) */   \
    unsigned lou_ = (LOU), hiu_ = (HIU);                                      \
    float2 f01 = __half22float2(*(const __half2*)&lou_);                      \
    float2 f23 = __half22float2(*(const __half2*)&hiu_);                      \
    float up_ = nxt_, dg_ = up_pipe;  /* dg = prev step's shuffle = [j-1] */  \
    if (w == 0) { if (lane == 0) { up_ = INFV; dg_ = (s_ == 0) ? 0.0f : INFV; } } \
    else if (lane == 0) { up_ = rbv[(K)]; dg_ = ((K) == 0) ? rcarry : rbv[(K) == 0 ? 0 : (K) - 1]; } \
    float oc0 = cur0, oc1 = cur1, oc2 = cur2;                                 \
    float A0 = fmin3(up_, cur0, dg_);                                         \
    float m0 = f01.x + A0;                                                    \
    float sv0 = fexp2(A0 - up_) + fexp2(A0 - cur0) + fexp2(A0 - dg_);         \
    float A1 = fmin3(m0, cur1, oc0);                                          \
    float m1 = f01.y + A1;                                                    \
    float sv1 = fmaf(sv0, fexp2(A1 - m0), fexp2(A1 - cur1) + fexp2(A1 - oc0));\
    float A2 = fmin3(m1, cur2, oc1);                                          \
    float m2 = f23.x + A2;                                                    \
    float sv2 = fmaf(sv1, fexp2(A2 - m1), fexp2(A2 - cur2) + fexp2(A2 - oc1));\
    float A3 = fmin3(m2, cur3, oc2);                                          \
    float m3 = f23.y + A3;                                                    \
    float sv3 = fmaf(sv2, fexp2(A3 - m2), fexp2(A3 - cur3) + fexp2(A3 - oc2));\
    float r0 = m0 - flog2(sv0);                                               \
    float r1 = m1 - flog2(sv1);                                               \
    float r2 = m2 - flog2(sv2);                                               \
    float r3 = m3 - flog2(sv3);                                               \
    int j_ = s_ - lane;                                                       \
    bool act_ = (lane < 50) && ((unsigned)j_ < 800u);                         \
    cur0 = act_ ? r0 : INFV; cur1 = act_ ? r1 : INFV;                         \
    cur2 = act_ ? r2 : INFV; cur3 = act_ ? r3 : INFV;                         \
    wrv[(K)] = cur3;                                                          \
    if (s_ == 848) res = cur3;                                                \
    up_pipe = nxt_;                                                           \
  } while (0)

#define STEP8(Q0, Q1, Q2, Q3) do {                                            \
    DO_STEP(0, Q0.x, Q0.y); DO_STEP(1, Q0.z, Q0.w);                           \
    DO_STEP(2, Q1.x, Q1.y); DO_STEP(3, Q1.z, Q1.w);                           \
    DO_STEP(4, Q2.x, Q2.y); DO_STEP(5, Q2.z, Q2.w);                           \
    DO_STEP(6, Q3.x, Q3.y); DO_STEP(7, Q3.z, Q3.w); } while (0)

  // prologue: every wave loads its local chunk 0
  PRE(a0, a1, a2, a3, 0);
  __syncthreads();

  for (int G = 0; G < NGC; ++G) {
    const int lc = G - LAGCH * w;
    if (lc >= 0 && lc < NLCB) {
      const int s0 = lc << 3;
      if ((lc & 1) == 0) {
        PRE(b0, b1, b2, b3, lc + 1);
        RINGLOAD;
        STEP8(a0, a1, a2, a3);
      } else {
        PRE(a0, a1, a2, a3, lc + 1);
        RINGLOAD;
        STEP8(b0, b1, b2, b3);
      }
      if (w < 3 && lane == 49) {
#pragma unroll
        for (int k = 0; k < 8; k++) {
          int j = s0 + k - 49;
          if ((unsigned)j < 800u) bnd[w][j & 127] = wrv[k];
        }
      }
      rcarry = rbv[7];
    }
    __syncthreads();
  }

  // res is pre-scaled; unscale (1/SCALE) and apply 0.001/16 in one constant.
  if (w == 3 && lane == 49) atomicAdd(&out[which], res * 4.3321699e-6f);

#undef PRE
#undef RINGLOAD
#undef DO_STEP
#undef STEP8
}

extern "C" void kernel_launch(void* const* d_in, const int* in_sizes, int n_in,
                              void* d_out, int out_size, void* d_ws, size_t ws_size,
                              hipStream_t stream) {
  const float* d         = (const float*)d_in[0];
  const int*   mel_len   = (const int*)d_in[1];
  const float* mel       = (const float*)d_in[2];
  const float* post      = (const float*)d_in[3];
  const float* target    = (const float*)d_in[4];
  const void*  src_mask  = d_in[5];
  const void*  pred_mask = d_in[6];
  float* out = (float*)d_out;

  int* flags = (int*)d_ws;
  __half* sig = (__half*)((char*)d_ws + 256);
  __half* Dsk = (__half*)((char*)d_ws + 256 + SIG_BYTES);
  size_t per = (size_t)HALF_PER_SLOT * sizeof(__half);  // 1.37 MB per problem
  size_t hdr = 256 + (size_t)SIG_BYTES;
  int slots = 0;
  if (ws_size > hdr) slots = (int)((ws_size - hdr) / per);
  if (slots > 32) slots = 32;

  (void)hipMemsetAsync(d_out, 0, 3 * sizeof(float), stream);
  detect_dloss_kernel<<<1, 256, 0, stream>>>(d, mel_len, src_mask, pred_mask, flags, out);
  if (slots < 1) return;
  sig_kernel<<<dim3(500, 3), 256, 0, stream>>>(mel, post, target, pred_mask, flags, sig);

  for (int base = 0; base < 32; base += slots) {
    int g = (32 - base < slots) ? (32 - base) : slots;
    cost_kernel<<<dim3(13, 13, g), 256, 0, stream>>>(sig, Dsk, base);
    dtw_kernel<<<g, 256, 0, stream>>>(Dsk, out, base);
  }
}

// Round 13
// 287.959 us; speedup vs baseline: 1.8849x; 1.2171x over previous
//
#include <hip/hip_runtime.h>
#include <hip/hip_fp16.h>

#define TT 800
#define CC 80
#define BB 16
#define SS 128
#define INFV 1e9f
#define NLCB 107          // local chunks per band (856 steps / 8; max s = 848)
#define LAGCH 8           // chunk lag between bands (64 steps >= 49 + 8 + margin)
#define NGC 131           // 107 + 3*8
#define BANDH 200         // rows per band (4 bands x 200 = 800)
#define HALF_PER_BAND (107*50*32)     // 171200
#define HALF_PER_SLOT (4*107*50*32)   // 684800
#define SCALE 14.426950408889634f     // (1/gamma)*log2(e), gamma=0.1
#define SIG_ELEMS (BB*TT*CC)          // 1,024,000 per array
#define SIG_BYTES (3*SIG_ELEMS*2)     // 6,144,000
#define NROWS (3*BB*TT)               // 38,400 rows
#define NORM_BYTES (NROWS*4)          // 153,600

typedef __attribute__((ext_vector_type(8))) _Float16 f16x8;
typedef __attribute__((ext_vector_type(4))) float f32x4;

// Bool masks may arrive as 1-byte numpy bools or int32 — detected at runtime.
__device__ inline bool mask_get(const void* p, int idx, int isInt) {
  if (isInt) return ((const int*)p)[idx] != 0;
  return ((const unsigned char*)p)[idx] != 0;
}

__device__ __forceinline__ float fexp2(float x) {
#if __has_builtin(__builtin_amdgcn_exp2f)
  return __builtin_amdgcn_exp2f(x);
#else
  return __expf(x * 0.6931471805599453f);
#endif
}
__device__ __forceinline__ float flog2(float x) {
#if __has_builtin(__builtin_amdgcn_logf)
  return __builtin_amdgcn_logf(x);
#else
  return __logf(x) * 1.4426950408889634f;
#endif
}
__device__ __forceinline__ float fmin3(float a, float b, float c) {
  return fminf(fminf(a, b), c);
}

// Wave-wide shift-up-by-1 on the VALU pipe (no LDS): DPP compose.
__device__ __forceinline__ float shift_up1(float x) {
  int xi = __builtin_bit_cast(int, x);
  int b = __builtin_amdgcn_update_dpp(xi, xi, 0x143, 0xf, 0xf, false); // row_bcast31
  b = __builtin_amdgcn_update_dpp(b, xi, 0x142, 0xf, 0xf, false);      // row_bcast15
  b = __builtin_amdgcn_update_dpp(b, xi, 0x111, 0xf, 0xf, false);      // row_shr:1
  return __builtin_bit_cast(float, b);
}

// Single block: detect mask element width, compute d_loss into out[2].
__global__ __launch_bounds__(256) void detect_dloss_kernel(
    const float* __restrict__ d, const int* __restrict__ mel_len,
    const void* __restrict__ src_mask, const void* __restrict__ pred_mask,
    int* __restrict__ flags, float* __restrict__ out)
{
  __shared__ int nzs, nzp;
  __shared__ float lb[BB];
  int tid = threadIdx.x;
  if (tid == 0) { nzs = 0; nzp = 0; }
  __syncthreads();
  const unsigned char* sm = (const unsigned char*)src_mask;
  const unsigned char* pm = (const unsigned char*)pred_mask;
  int f = 0;
  for (int i = tid; i < BB * SS; i += 256) if ((i & 3) && sm[i]) f = 1;
  if (f) atomicOr(&nzs, 1);
  f = 0;
  for (int i = tid; i < BB * TT; i += 256) if ((i & 3) && pm[i]) f = 1;
  if (f) atomicOr(&nzp, 1);
  __syncthreads();
  int isIntS = nzs ? 0 : 1;
  if (tid == 0) { flags[0] = isIntS; flags[1] = nzp ? 0 : 1; }

  int b = tid >> 4, k = tid & 15;
  float sd = 0.f, so = 0.f;
  for (int s = k; s < SS; s += 16) {
    bool m = mask_get(src_mask, b * SS + s, isIntS);
    if (!m) { sd += d[b * SS + s]; so += 1.f; }
  }
  for (int off = 8; off; off >>= 1) {
    sd += __shfl_down(sd, off, 16);
    so += __shfl_down(so, off, 16);
  }
  if (k == 0) lb[b] = fabsf((float)mel_len[b] - sd) / so;
  __syncthreads();
  if (tid == 0) {
    float s = 0.f;
    for (int i = 0; i < BB; i++) s += lb[i];
    out[2] = s / (float)BB;
  }
}

// Sigmoid pre-pass: sig[0]=sigmoid(masked mel), sig[1]=sigmoid(post),
// sig[2]=sigmoid(target), each [16][800][80] fp16. 8 elems/thread, vectorized.
__global__ __launch_bounds__(256) void sig_kernel(
    const float* __restrict__ mel, const float* __restrict__ post,
    const float* __restrict__ target, const void* __restrict__ pred_mask,
    const int* __restrict__ flags, __half* __restrict__ sig)
{
  int arr = blockIdx.y;
  const float* src = arr == 0 ? mel : (arr == 1 ? post : target);
  __half* dst = sig + (size_t)arr * SIG_ELEMS;
  int pack = blockIdx.x * 256 + threadIdx.x;
  if (pack >= SIG_ELEMS / 8) return;
  size_t e0 = (size_t)pack * 8;
  float4 v0 = *(const float4*)(src + e0);
  float4 v1 = *(const float4*)(src + e0 + 4);
  if (arr == 0) {
    int bt = (int)(e0 / CC);
    if (mask_get(pred_mask, bt, flags[1])) {
      v0 = make_float4(0.f, 0.f, 0.f, 0.f);
      v1 = make_float4(0.f, 0.f, 0.f, 0.f);
    }
  }
  float f[8] = {v0.x, v0.y, v0.z, v0.w, v1.x, v1.y, v1.z, v1.w};
  union { __half h[8]; uint4 u; } o;
#pragma unroll
  for (int i = 0; i < 8; i++) o.h[i] = __float2half(1.f / (1.f + __expf(-f[i])));
  *(uint4*)(dst + e0) = o.u;
}

// Row squared-norms of all sig rows: norms[arr*12800 + b*800 + t] fp32.
__global__ __launch_bounds__(256) void rnorm_kernel(
    const __half* __restrict__ sig, float* __restrict__ norms)
{
  int row = blockIdx.x * 256 + threadIdx.x;
  if (row >= NROWS) return;
  const __half* p = sig + (size_t)row * CC;
  float s = 0.f;
#pragma unroll
  for (int c = 0; c < CC; c += 8) {
    uint4 u = *(const uint4*)(p + c);
    const __half2* h2 = (const __half2*)&u;
#pragma unroll
    for (int q = 0; q < 4; q++) {
      float2 fv = __half22float2(h2[q]);
      s = fmaf(fv.x, fv.x, s);
      s = fmaf(fv.y, fv.y, s);
    }
  }
  norms[row] = s;
}

// MFMA cost kernel: D[i][j] = |x_i|^2 + |y_j|^2 - 2 x_i.y_j  (pre-scaled),
// stored in the skew-1 chunked layout consumed by dtw. One wave per
// (problem, 16-row i-strip); A-frags in registers (K zero-padded 80->96);
// 50 j-tiles x 3 mfma_f32_16x16x32_f16. C/D layout per verified m89 mapping.
__global__ __launch_bounds__(64) void costm_kernel(
    const __half* __restrict__ sig, const float* __restrict__ norms,
    __half* __restrict__ Dsk, int probBase)
{
  int slot = blockIdx.y;
  int prob = probBase + slot;
  int which = prob >> 4, b = prob & 15;
  const __half* X = sig + (size_t)which * SIG_ELEMS + (size_t)b * TT * CC;
  const __half* Y = sig + (size_t)2 * SIG_ELEMS + (size_t)b * TT * CC;
  const float* nx = norms + which * (BB * TT) + b * TT;
  const float* ny = norms + 2 * (BB * TT) + b * TT;
  int lane = threadIdx.x;
  int mrow = lane & 15, kh = lane >> 4;   // A/B frag: row/col = lane&15, k-group = lane>>4
  int i0 = blockIdx.x * 16;

  // A fragments: X row i0+mrow, k = c*32 + kh*8 .. +7 (zero beyond K=80)
  const __half* xr = X + (size_t)(i0 + mrow) * CC;
  uint4 az0 = *(const uint4*)(xr + kh * 8);
  uint4 az1 = *(const uint4*)(xr + 32 + kh * 8);
  uint4 az2 = make_uint4(0, 0, 0, 0);
  if (kh < 2) az2 = *(const uint4*)(xr + 64 + kh * 8);
  f16x8 a0 = __builtin_bit_cast(f16x8, az0);
  f16x8 a1 = __builtin_bit_cast(f16x8, az1);
  f16x8 a2 = __builtin_bit_cast(f16x8, az2);

  // norms for this lane's 4 output rows (C/D: rows (lane>>4)*4 + r)
  int i4 = i0 + (lane >> 4) * 4;
  float4 nx4 = *(const float4*)(nx + i4);

  int band = i4 / BANDH;
  int l = (i4 % BANDH) >> 2;
  __half* obase = Dsk + (size_t)slot * HALF_PER_SLOT +
                  (size_t)band * HALF_PER_BAND + (size_t)l * 32;

  const __half* yr = Y + (size_t)mrow * CC;
  for (int j0 = 0; j0 < TT; j0 += 16) {
    uint4 bz0 = *(const uint4*)(yr + kh * 8);
    uint4 bz1 = *(const uint4*)(yr + 32 + kh * 8);
    uint4 bz2 = make_uint4(0, 0, 0, 0);
    if (kh < 2) bz2 = *(const uint4*)(yr + 64 + kh * 8);
    f32x4 acc = {0.f, 0.f, 0.f, 0.f};
    acc = __builtin_amdgcn_mfma_f32_16x16x32_f16(a0, __builtin_bit_cast(f16x8, bz0), acc, 0, 0, 0);
    acc = __builtin_amdgcn_mfma_f32_16x16x32_f16(a1, __builtin_bit_cast(f16x8, bz1), acc, 0, 0, 0);
    acc = __builtin_amdgcn_mfma_f32_16x16x32_f16(a2, __builtin_bit_cast(f16x8, bz2), acc, 0, 0, 0);

    int j = j0 + mrow;            // C/D col = lane&15
    float nyv = ny[j];
    int s = j + l;
    int ch = s >> 3, kk = s & 7;
    union { __half h[4]; uint2 u; } cv;
#pragma unroll
    for (int r = 0; r < 4; r++) {
      float nxv = (r == 0) ? nx4.x : (r == 1) ? nx4.y : (r == 2) ? nx4.z : nx4.w;
      cv.h[r] = __float2half((nxv + nyv - 2.0f * acc[r]) * SCALE);
    }
    *(uint2*)(obase + (size_t)ch * 1600 + kk * 4) = cv.u;
    yr += (size_t)16 * CC;
  }
}

// Wave-pipelined soft-DTW: 4 waves = 4 bands of 200 rows (lanes 0..49, 4 rows
// each), skew-1 (lane l at col j = s-l), consume-immediately DPP wiring.
// [frozen at round-12 best: 228 us, absmax 0]
__global__ __launch_bounds__(256) void dtw_kernel(
    const __half* __restrict__ Dsk, float* __restrict__ out, int probBase)
{
  __shared__ float bnd[3][128];
  const int tid = threadIdx.x;
  const int w = tid >> 6, lane = tid & 63;
  const int slot = blockIdx.x;
  const int prob = probBase + slot;
  const int which = prob >> 4;
  const int lclamp = lane < 49 ? lane : 49;
  const __half* Db = Dsk + (size_t)slot * HALF_PER_SLOT + (size_t)w * HALF_PER_BAND;

  float cur0 = INFV, cur1 = INFV, cur2 = INFV, cur3 = INFV;
  float up_pipe = INFV, rcarry = INFV, res = 0.f;
  float rbv[8], wrv[8];
#pragma unroll
  for (int k = 0; k < 8; k++) { rbv[k] = INFV; wrv[k] = INFV; }

  uint4 a0, a1, a2, a3, b0, b1, b2, b3;

#define PRE(P0, P1, P2, P3, LCN) do { if ((LCN) < NLCB) {                     \
    const uint4* p_ = (const uint4*)(Db + ((size_t)(LCN) * 50 + lclamp) * 32);\
    P0 = p_[0]; P1 = p_[1]; P2 = p_[2]; P3 = p_[3]; } } while (0)

#define RINGLOAD do { if (w) {                                                \
    const float4* rp_ = (const float4*)&bnd[w - 1][s0 & 127];                 \
    float4 ra_ = rp_[0], rc_ = rp_[1];                                        \
    rbv[0] = ra_.x; rbv[1] = ra_.y; rbv[2] = ra_.z; rbv[3] = ra_.w;           \
    rbv[4] = rc_.x; rbv[5] = rc_.y; rbv[6] = rc_.z; rbv[7] = rc_.w; } } while (0)

#define DO_STEP(K, LOU, HIU) do {                                             \
    const int s_ = s0 + (K);                                                  \
    float nxt_ = shift_up1(cur3);   /* R[4l-1][j] this step (junk lane0) */   \
    unsigned lou_ = (LOU), hiu_ = (HIU);                                      \
    float2 f01 = __half22float2(*(const __half2*)&lou_);                      \
    float2 f23 = __half22float2(*(const __half2*)&hiu_);                      \
    float up_ = nxt_, dg_ = up_pipe;  /* dg = prev step's shuffle = [j-1] */  \
    if (w == 0) { if (lane == 0) { up_ = INFV; dg_ = (s_ == 0) ? 0.0f : INFV; } } \
    else if (lane == 0) { up_ = rbv[(K)]; dg_ = ((K) == 0) ? rcarry : rbv[(K) == 0 ? 0 : (K) - 1]; } \
    float oc0 = cur0, oc1 = cur1, oc2 = cur2;                                 \
    float A0 = fmin3(up_, cur0, dg_);                                         \
    float m0 = f01.x + A0;                                                    \
    float sv0 = fexp2(A0 - up_) + fexp2(A0 - cur0) + fexp2(A0 - dg_);         \
    float A1 = fmin3(m0, cur1, oc0);                                          \
    float m1 = f01.y + A1;                                                    \
    float sv1 = fmaf(sv0, fexp2(A1 - m0), fexp2(A1 - cur1) + fexp2(A1 - oc0));\
    float A2 = fmin3(m1, cur2, oc1);                                          \
    float m2 = f23.x + A2;                                                    \
    float sv2 = fmaf(sv1, fexp2(A2 - m1), fexp2(A2 - cur2) + fexp2(A2 - oc1));\
    float A3 = fmin3(m2, cur3, oc2);                                          \
    float m3 = f23.y + A3;                                                    \
    float sv3 = fmaf(sv2, fexp2(A3 - m2), fexp2(A3 - cur3) + fexp2(A3 - oc2));\
    float r0 = m0 - flog2(sv0);                                               \
    float r1 = m1 - flog2(sv1);                                               \
    float r2 = m2 - flog2(sv2);                                               \
    float r3 = m3 - flog2(sv3);                                               \
    int j_ = s_ - lane;                                                       \
    bool act_ = (lane < 50) && ((unsigned)j_ < 800u);                         \
    cur0 = act_ ? r0 : INFV; cur1 = act_ ? r1 : INFV;                         \
    cur2 = act_ ? r2 : INFV; cur3 = act_ ? r3 : INFV;                         \
    wrv[(K)] = cur3;                                                          \
    if (s_ == 848) res = cur3;                                                \
    up_pipe = nxt_;                                                           \
  } while (0)

#define STEP8(Q0, Q1, Q2, Q3) do {                                            \
    DO_STEP(0, Q0.x, Q0.y); DO_STEP(1, Q0.z, Q0.w);                           \
    DO_STEP(2, Q1.x, Q1.y); DO_STEP(3, Q1.z, Q1.w);                           \
    DO_STEP(4, Q2.x, Q2.y); DO_STEP(5, Q2.z, Q2.w);                           \
    DO_STEP(6, Q3.x, Q3.y); DO_STEP(7, Q3.z, Q3.w); } while (0)

  // prologue: every wave loads its local chunk 0
  PRE(a0, a1, a2, a3, 0);
  __syncthreads();

  for (int G = 0; G < NGC; ++G) {
    const int lc = G - LAGCH * w;
    if (lc >= 0 && lc < NLCB) {
      const int s0 = lc << 3;
      if ((lc & 1) == 0) {
        PRE(b0, b1, b2, b3, lc + 1);
        RINGLOAD;
        STEP8(a0, a1, a2, a3);
      } else {
        PRE(a0, a1, a2, a3, lc + 1);
        RINGLOAD;
        STEP8(b0, b1, b2, b3);
      }
      if (w < 3 && lane == 49) {
#pragma unroll
        for (int k = 0; k < 8; k++) {
          int j = s0 + k - 49;
          if ((unsigned)j < 800u) bnd[w][j & 127] = wrv[k];
        }
      }
      rcarry = rbv[7];
    }
    __syncthreads();
  }

  // res is pre-scaled; unscale (1/SCALE) and apply 0.001/16 in one constant.
  if (w == 3 && lane == 49) atomicAdd(&out[which], res * 4.3321699e-6f);

#undef PRE
#undef RINGLOAD
#undef DO_STEP
#undef STEP8
}

extern "C" void kernel_launch(void* const* d_in, const int* in_sizes, int n_in,
                              void* d_out, int out_size, void* d_ws, size_t ws_size,
                              hipStream_t stream) {
  const float* d         = (const float*)d_in[0];
  const int*   mel_len   = (const int*)d_in[1];
  const float* mel       = (const float*)d_in[2];
  const float* post      = (const float*)d_in[3];
  const float* target    = (const float*)d_in[4];
  const void*  src_mask  = d_in[5];
  const void*  pred_mask = d_in[6];
  float* out = (float*)d_out;

  int* flags = (int*)d_ws;
  __half* sig = (__half*)((char*)d_ws + 256);
  float* norms = (float*)((char*)d_ws + 256 + SIG_BYTES);
  __half* Dsk = (__half*)((char*)d_ws + 256 + SIG_BYTES + NORM_BYTES);
  size_t per = (size_t)HALF_PER_SLOT * sizeof(__half);  // 1.37 MB per problem
  size_t hdr = 256 + (size_t)SIG_BYTES + (size_t)NORM_BYTES;
  int slots = 0;
  if (ws_size > hdr) slots = (int)((ws_size - hdr) / per);
  if (slots > 32) slots = 32;

  (void)hipMemsetAsync(d_out, 0, 3 * sizeof(float), stream);
  detect_dloss_kernel<<<1, 256, 0, stream>>>(d, mel_len, src_mask, pred_mask, flags, out);
  if (slots < 1) return;
  sig_kernel<<<dim3(500, 3), 256, 0, stream>>>(mel, post, target, pred_mask, flags, sig);
  rnorm_kernel<<<150, 256, 0, stream>>>(sig, norms);

  for (int base = 0; base < 32; base += slots) {
    int g = (32 - base < slots) ? (32 - base) : slots;
    costm_kernel<<<dim3(50, g), 64, 0, stream>>>(sig, norms, Dsk, base);
    dtw_kernel<<<g, 256, 0, stream>>>(Dsk, out, base);
  }
}